// Round 3
// baseline (1500.593 us; speedup 1.0000x reference)
//
#include <hip/hip_runtime.h>
#include <hip/hip_bf16.h>

// MACE layer forward, MI355X (gfx950).
// Inputs/outputs are FLOAT32 (per reference dtypes). Round-1/2 NaNs were
// caused by reading f32 buffers as bf16 (low half-words decode to NaN/huge).
// Internal intermediates (W_rad2 LDS copy, h, agg) are bf16 (~0.4% rel err,
// threshold is ~6% of output scale). Index clamps kept as cheap insurance.

#define NN 10000
#define EE 320000
#define CCH 128
#define NRB 8
#define NHID 64
#define FEPS 0.17677669529663687f

__device__ __forceinline__ float bflo(unsigned u) { return __uint_as_float(u << 16); }
__device__ __forceinline__ float bfhi(unsigned u) { return __uint_as_float(u & 0xffff0000u); }
__device__ __forceinline__ float b2f(__hip_bfloat16 x) { return __bfloat162float(x); }
// round-to-nearest-even f32 -> bf16 (as ushort)
__device__ __forceinline__ unsigned short f2bu(float f) {
    unsigned u = __float_as_uint(f);
    return (unsigned short)((u + 0x7FFFu + ((u >> 16) & 1u)) >> 16);
}
__device__ __forceinline__ unsigned pack2(float a, float b) {
    return (unsigned)f2bu(a) | ((unsigned)f2bu(b) << 16);
}

// ---------------- CSR build ----------------
__global__ void k_hist(const int* __restrict__ recv, int* __restrict__ cnt) {
    int e = blockIdx.x * blockDim.x + threadIdx.x;
    if (e < EE) {
        int r = recv[e];
        r = ((unsigned)r < NN) ? r : 0;
        atomicAdd(&cnt[r], 1);
    }
}

__global__ void k_scan(const int* __restrict__ cnt, int* __restrict__ offs,
                       int* __restrict__ cur) {
    __shared__ int sums[1024];
    const int t = threadIdx.x;
    const int chunk = (NN + 1023) / 1024;  // 10
    const int start = t * chunk;
    int local = 0;
    for (int i = 0; i < chunk; i++) {
        int idx = start + i;
        if (idx < NN) local += cnt[idx];
    }
    sums[t] = local;
    __syncthreads();
    for (int ofs = 1; ofs < 1024; ofs <<= 1) {
        int u = (t >= ofs) ? sums[t - ofs] : 0;
        __syncthreads();
        sums[t] += u;
        __syncthreads();
    }
    int base = (t == 0) ? 0 : sums[t - 1];
    for (int i = 0; i < chunk; i++) {
        int idx = start + i;
        if (idx < NN) {
            offs[idx] = base;
            cur[idx] = base;
            base += cnt[idx];
        }
    }
    if (t == 0) offs[NN] = sums[1023];
}

__global__ void k_fill(const int* __restrict__ recv, int* __restrict__ cur,
                       int* __restrict__ csr) {
    int e = blockIdx.x * blockDim.x + threadIdx.x;
    if (e < EE) {
        int r = recv[e];
        r = ((unsigned)r < NN) ? r : 0;
        int slot = atomicAdd(&cur[r], 1);
        if ((unsigned)slot < EE) csr[slot] = e;
    }
}

// ---------------- node pre: h_s = s@W_up_s, h_v = v@W_up_v (bf16 out) ------
__global__ __launch_bounds__(512) void k_pre(
    const float* __restrict__ node_feats,
    const float* __restrict__ W_up_s,
    const float* __restrict__ W_up_v,
    __hip_bfloat16* __restrict__ h) {
    const int sub = threadIdx.x >> 7, d = threadIdx.x & 127;
    const int n = blockIdx.x * 4 + sub;
    __shared__ float sv[4][512];
    const float* nf = node_feats + (size_t)n * 512;
    ((float4*)sv[sub])[d] = ((const float4*)nf)[d];
    __syncthreads();
    float as = 0.f, a0 = 0.f, a1 = 0.f, a2 = 0.f;
    for (int c = 0; c < 128; c++) {
        const float wus = W_up_s[c * 128 + d];
        const float wuv = W_up_v[c * 128 + d];
        as += sv[sub][c] * wus;
        a0 += sv[sub][128 + c * 3 + 0] * wuv;
        a1 += sv[sub][128 + c * 3 + 1] * wuv;
        a2 += sv[sub][128 + c * 3 + 2] * wuv;
    }
    unsigned short* hn = (unsigned short*)(h + (size_t)n * 512);
    hn[d] = f2bu(as);
    hn[128 + d * 3 + 0] = f2bu(a0);
    hn[128 + d * 3 + 1] = f2bu(a1);
    hn[128 + d * 3 + 2] = f2bu(a2);
}

// ---------------- edge gather: per-receiver block ----------------
// 256 threads = 4 waves; each wave processes 8 edges per W_rad2 LDS sweep.
// lane owns channels 2l, 2l+1.
__global__ __launch_bounds__(256, 1) void k_edge(
    const float* __restrict__ vectors,
    const float* __restrict__ radial,
    const int* __restrict__ senders,
    const float* __restrict__ W_rad1,
    const float* __restrict__ W_rad2,
    const __hip_bfloat16* __restrict__ h,
    const int* __restrict__ offs, const int* __restrict__ csr,
    __hip_bfloat16* __restrict__ agg_g) {
    __shared__ __align__(16) unsigned short w2[64 * 640];  // 80 KB bf16
    __shared__ float agg[512];
    const int n = blockIdx.x, tid = threadIdx.x;
    const int lane = tid & 63, wv = tid >> 6;
    const int c0 = 2 * lane;
    // stage W_rad2 (f32 global -> bf16 LDS), vectorized 4 floats/iter
    for (int i = tid; i < 10240; i += 256) {
        const float4 f = ((const float4*)W_rad2)[i];
        ((uint2*)w2)[i] = make_uint2(pack2(f.x, f.y), pack2(f.z, f.w));
    }
    for (int i = tid; i < 512; i += 256) agg[i] = 0.f;
    float w1r[NRB];
#pragma unroll
    for (int r = 0; r < NRB; r++) w1r[r] = W_rad1[r * 64 + lane];
    __syncthreads();
    const int start = offs[n];
    const int deg = offs[n + 1] - start;
    float accs0 = 0, accs1 = 0;
    float accv00 = 0, accv01 = 0, accv02 = 0, accv10 = 0, accv11 = 0, accv12 = 0;
    for (int base = wv * 8; base < deg; base += 32) {
        const int m = min(8, deg - base);
        int ej[8];
#pragma unroll
        for (int t = 0; t < 8; t++) {
            int e = csr[start + base + ((t < m) ? t : 0)];
            ej[t] = ((unsigned)e < EE) ? e : 0;  // clamp: OOB -> finite wrong
        }
        // radial hidden: lane l computes hid unit h=l for each of the 8 edges
        float hid[8];
#pragma unroll
        for (int t = 0; t < 8; t++) {
            const float4 e0 = *(const float4*)(radial + (size_t)ej[t] * 8);
            const float4 e1 = *(const float4*)(radial + (size_t)ej[t] * 8 + 4);
            float ha = e0.x * w1r[0] + e0.y * w1r[1] + e0.z * w1r[2] + e0.w * w1r[3]
                     + e1.x * w1r[4] + e1.y * w1r[5] + e1.z * w1r[6] + e1.w * w1r[7];
            hid[t] = ha / (1.f + __expf(-ha));
        }
        // w = hid @ W_rad2 for 8 edges; 5 k-paths x 2 channels per lane
        float wa[8][10];
#pragma unroll
        for (int t = 0; t < 8; t++)
#pragma unroll
            for (int q = 0; q < 10; q++) wa[t][q] = 0.f;
#pragma unroll 2
        for (int hh_i = 0; hh_i < 64; hh_i++) {
            const unsigned short* row = w2 + hh_i * 640 + c0;
            const unsigned u0 = *(const unsigned*)(row);
            const unsigned u1 = *(const unsigned*)(row + 128);
            const unsigned u2 = *(const unsigned*)(row + 256);
            const unsigned u3 = *(const unsigned*)(row + 384);
            const unsigned u4 = *(const unsigned*)(row + 512);
            const float f0 = bflo(u0), f1 = bfhi(u0);
            const float f2 = bflo(u1), f3 = bfhi(u1);
            const float f4 = bflo(u2), f5 = bfhi(u2);
            const float f6 = bflo(u3), f7 = bfhi(u3);
            const float f8 = bflo(u4), f9 = bfhi(u4);
#pragma unroll
            for (int t = 0; t < 8; t++) {
                const float hh = __int_as_float(
                    __builtin_amdgcn_readlane(__float_as_int(hid[t]), hh_i));
                wa[t][0] += hh * f0; wa[t][1] += hh * f1;
                wa[t][2] += hh * f2; wa[t][3] += hh * f3;
                wa[t][4] += hh * f4; wa[t][5] += hh * f5;
                wa[t][6] += hh * f6; wa[t][7] += hh * f7;
                wa[t][8] += hh * f8; wa[t][9] += hh * f9;
            }
        }
        // messages + accumulate
#pragma unroll
        for (int t = 0; t < 8; t++) {
            if (t < m) {
                const int e = ej[t];
                const float vx = vectors[e * 3 + 0];
                const float vy = vectors[e * 3 + 1];
                const float vz = vectors[e * 3 + 2];
                const float inr =
                    1.7320508075688772f / (sqrtf(vx * vx + vy * vy + vz * vz) + 1e-9f);
                const float y0 = vx * inr, y1 = vy * inr, y2 = vz * inr;
                int j = senders[e];
                j = ((unsigned)j < NN) ? j : 0;  // clamp
                const __hip_bfloat16* hj = h + (size_t)j * 512;
                const unsigned us = *(const unsigned*)(hj + c0);
                const float sj0 = bflo(us), sj1 = bfhi(us);
                const __hip_bfloat16* hv = hj + 128 + c0 * 3;
                const unsigned ua = *(const unsigned*)(hv);
                const unsigned ub = *(const unsigned*)(hv + 2);
                const unsigned uc = *(const unsigned*)(hv + 4);
                const float vj00 = bflo(ua), vj01 = bfhi(ua), vj02 = bflo(ub);
                const float vj10 = bfhi(ub), vj11 = bflo(uc), vj12 = bfhi(uc);
                const float dot0 = vj00 * y0 + vj01 * y1 + vj02 * y2;
                const float dot1 = vj10 * y0 + vj11 * y1 + vj12 * y2;
                const float cr00 = vj01 * y2 - vj02 * y1;
                const float cr01 = vj02 * y0 - vj00 * y2;
                const float cr02 = vj00 * y1 - vj01 * y0;
                const float cr10 = vj11 * y2 - vj12 * y1;
                const float cr11 = vj12 * y0 - vj10 * y2;
                const float cr12 = vj10 * y1 - vj11 * y0;
                accs0 += wa[t][0] * sj0 + wa[t][6] * dot0;
                accs1 += wa[t][1] * sj1 + wa[t][7] * dot1;
                accv00 += wa[t][2] * sj0 * y0 + wa[t][4] * vj00 + wa[t][8] * cr00;
                accv01 += wa[t][2] * sj0 * y1 + wa[t][4] * vj01 + wa[t][8] * cr01;
                accv02 += wa[t][2] * sj0 * y2 + wa[t][4] * vj02 + wa[t][8] * cr02;
                accv10 += wa[t][3] * sj1 * y0 + wa[t][5] * vj10 + wa[t][9] * cr10;
                accv11 += wa[t][3] * sj1 * y1 + wa[t][5] * vj11 + wa[t][9] * cr11;
                accv12 += wa[t][3] * sj1 * y2 + wa[t][5] * vj12 + wa[t][9] * cr12;
            }
        }
    }
    atomicAdd(&agg[c0 + 0], accs0);
    atomicAdd(&agg[c0 + 1], accs1);
    atomicAdd(&agg[128 + c0 * 3 + 0], accv00);
    atomicAdd(&agg[128 + c0 * 3 + 1], accv01);
    atomicAdd(&agg[128 + c0 * 3 + 2], accv02);
    atomicAdd(&agg[128 + (c0 + 1) * 3 + 0], accv10);
    atomicAdd(&agg[128 + (c0 + 1) * 3 + 1], accv11);
    atomicAdd(&agg[128 + (c0 + 1) * 3 + 2], accv12);
    __syncthreads();
    unsigned short* og = (unsigned short*)(agg_g + (size_t)n * 512);
    for (int i = tid; i < 512; i += 256) og[i] = f2bu(agg[i]);
}

// ---------------- node post: down/prod/lin/skip/readout ----------------
__global__ __launch_bounds__(512) void k_post(
    const float* __restrict__ node_feats,
    const int* __restrict__ specie,
    const __hip_bfloat16* __restrict__ agg_g,
    const float* __restrict__ W_down_s,
    const float* __restrict__ W_down_v,
    const float* __restrict__ W_skip_s,
    const float* __restrict__ W_skip_v,
    const float* __restrict__ W_prod_s,
    const float* __restrict__ W_prod_v,
    const float* __restrict__ W_lin_s,
    const float* __restrict__ W_lin_v,
    const float* __restrict__ W_ro,
    float* __restrict__ d_out) {
    const int sub = threadIdx.x >> 7, d = threadIdx.x & 127;
    const int n = blockIdx.x * 4 + sub;
    __shared__ float sv[4][512];
    __shared__ float ag[4][512];
    __shared__ float pl[4][512];
    __shared__ float red[4][2];
    const float* nf = node_feats + (size_t)n * 512;
    const __hip_bfloat16* agp = agg_g + (size_t)n * 512;
    ((float4*)sv[sub])[d] = ((const float4*)nf)[d];
    for (int i = d; i < 512; i += 128) ag[sub][i] = b2f(agp[i]);
    __syncthreads();
    int spec = specie[n];
    spec = ((unsigned)spec < 10) ? spec : 0;
    const float* Wss = W_skip_s + (size_t)spec * 16384;
    const float* Wsv = W_skip_v + (size_t)spec * 16384;
    float scs = 0, scv0 = 0, scv1 = 0, scv2 = 0, fs = 0, fv0 = 0, fv1 = 0, fv2 = 0;
    for (int c = 0; c < 128; c++) {
        const float s_c = sv[sub][c];
        const float v0 = sv[sub][128 + c * 3 + 0];
        const float v1 = sv[sub][128 + c * 3 + 1];
        const float v2 = sv[sub][128 + c * 3 + 2];
        const float a_c = ag[sub][c];
        const float a0 = ag[sub][128 + c * 3 + 0];
        const float a1 = ag[sub][128 + c * 3 + 1];
        const float a2 = ag[sub][128 + c * 3 + 2];
        const float wss = Wss[c * 128 + d];
        const float wsv = Wsv[c * 128 + d];
        const float wds = W_down_s[c * 128 + d];
        const float wdv = W_down_v[c * 128 + d];
        scs += s_c * wss;
        scv0 += v0 * wsv; scv1 += v1 * wsv; scv2 += v2 * wsv;
        fs += a_c * wds;
        fv0 += a0 * wdv; fv1 += a1 * wdv; fv2 += a2 * wdv;
    }
    fs *= FEPS; fv0 *= FEPS; fv1 *= FEPS; fv2 *= FEPS;
    const float ps = fs * W_prod_s[spec * 384 + d]
                   + fs * fs * W_prod_s[spec * 384 + 128 + d]
                   + (fv0 * fv0 + fv1 * fv1 + fv2 * fv2) * W_prod_s[spec * 384 + 256 + d];
    const float pw0 = W_prod_v[spec * 256 + d];
    const float pw1 = W_prod_v[spec * 256 + 128 + d];
    const float pv0 = fv0 * pw0 + fs * fv0 * pw1;
    const float pv1 = fv1 * pw0 + fs * fv1 * pw1;
    const float pv2 = fv2 * pw0 + fs * fv2 * pw1;
    pl[sub][d] = ps;
    pl[sub][128 + d * 3 + 0] = pv0;
    pl[sub][128 + d * 3 + 1] = pv1;
    pl[sub][128 + d * 3 + 2] = pv2;
    __syncthreads();
    float outs = scs, ov0 = scv0, ov1 = scv1, ov2 = scv2;
    for (int c = 0; c < 128; c++) {
        const float wls = W_lin_s[c * 128 + d];
        const float wlv = W_lin_v[c * 128 + d];
        outs += pl[sub][c] * wls;
        ov0 += pl[sub][128 + c * 3 + 0] * wlv;
        ov1 += pl[sub][128 + c * 3 + 1] * wlv;
        ov2 += pl[sub][128 + c * 3 + 2] * wlv;
    }
    float* o1 = d_out + NN + (size_t)n * 512;
    o1[d] = outs;
    o1[128 + d * 3 + 0] = ov0;
    o1[128 + d * 3 + 1] = ov1;
    o1[128 + d * 3 + 2] = ov2;
    float r = outs * W_ro[d];
#pragma unroll
    for (int o = 32; o > 0; o >>= 1) r += __shfl_down(r, o);
    const int lane = threadIdx.x & 63;
    const int wv_in_sub = (threadIdx.x >> 6) & 1;
    if (lane == 0) red[sub][wv_in_sub] = r;
    __syncthreads();
    if (d == 0) d_out[n] = red[sub][0] + red[sub][1];
}

extern "C" void kernel_launch(void* const* d_in, const int* in_sizes, int n_in,
                              void* d_out, int out_size, void* d_ws, size_t ws_size,
                              hipStream_t stream) {
    const float* vectors    = (const float*)d_in[0];
    const float* node_feats = (const float*)d_in[1];
    const int*   specie     = (const int*)d_in[2];
    const float* radial     = (const float*)d_in[3];
    const int*   senders    = (const int*)d_in[4];
    const int*   receivers  = (const int*)d_in[5];
    const float* W_up_s     = (const float*)d_in[6];
    const float* W_up_v     = (const float*)d_in[7];
    const float* W_rad1     = (const float*)d_in[8];
    const float* W_rad2     = (const float*)d_in[9];
    const float* W_down_s   = (const float*)d_in[10];
    const float* W_down_v   = (const float*)d_in[11];
    const float* W_skip_s   = (const float*)d_in[12];
    const float* W_skip_v   = (const float*)d_in[13];
    const float* W_prod_s   = (const float*)d_in[14];
    const float* W_prod_v   = (const float*)d_in[15];
    const float* W_lin_s    = (const float*)d_in[16];
    const float* W_lin_v    = (const float*)d_in[17];
    const float* W_ro       = (const float*)d_in[18];
    float* out = (float*)d_out;

    // compact workspace carve (~22 MB): CSR machinery first, bf16 h/agg after
    char* w = (char*)d_ws;
    auto align256 = [](size_t x) { return (x + 255) & ~(size_t)255; };
    int* cnt  = (int*)w;              w += align256((size_t)NN * 4);
    int* offs = (int*)w;              w += align256((size_t)(NN + 1) * 4);
    int* cur  = (int*)w;              w += align256((size_t)NN * 4);
    int* csr  = (int*)w;              w += align256((size_t)EE * 4);
    __hip_bfloat16* h     = (__hip_bfloat16*)w;  w += align256((size_t)NN * 512 * 2);
    __hip_bfloat16* agg_g = (__hip_bfloat16*)w;

    hipMemsetAsync(cnt, 0, NN * sizeof(int), stream);
    k_hist<<<(EE + 255) / 256, 256, 0, stream>>>(receivers, cnt);
    k_scan<<<1, 1024, 0, stream>>>(cnt, offs, cur);
    k_fill<<<(EE + 255) / 256, 256, 0, stream>>>(receivers, cur, csr);
    k_pre<<<NN / 4, 512, 0, stream>>>(node_feats, W_up_s, W_up_v, h);
    k_edge<<<NN, 256, 0, stream>>>(vectors, radial, senders, W_rad1, W_rad2,
                                   h, offs, csr, agg_g);
    k_post<<<NN / 4, 512, 0, stream>>>(node_feats, specie, agg_g,
                                       W_down_s, W_down_v, W_skip_s, W_skip_v,
                                       W_prod_s, W_prod_v, W_lin_s, W_lin_v,
                                       W_ro, out);
}

// Round 4
// 1044.582 us; speedup vs baseline: 1.4365x; 1.4365x over previous
//
#include <hip/hip_runtime.h>
#include <hip/hip_bf16.h>

// MACE layer forward, MI355X (gfx950). f32 I/O, bf16 internals.
// Round 4: MFMA edge kernel. 1 wave/receiver; 16-edge groups as MFMA M-rows;
// hid@W_rad2 via mfma_f32_16x16x32_bf16 with B-frags from a pre-transposed
// bf16 w2t[640][64] table in ws (L2-resident). No 80KB LDS -> occupancy up.
// Tile-groups {t,t+8..t+32} give each lane all 5 path weights for channel
// c=16t+(lane&15) directly in the C-frag; per-wave accumulators, no atomics.

#define NN 10000
#define EE 320000
#define FEPS 0.17677669529663687f

typedef __attribute__((ext_vector_type(4))) float f32x4;
typedef __attribute__((ext_vector_type(8))) short s16x8;

__device__ __forceinline__ float bflo(unsigned u) { return __uint_as_float(u << 16); }
__device__ __forceinline__ float bfhi(unsigned u) { return __uint_as_float(u & 0xffff0000u); }
__device__ __forceinline__ float bfu(unsigned short u) { return __uint_as_float((unsigned)u << 16); }
__device__ __forceinline__ float b2f(__hip_bfloat16 x) { return __bfloat162float(x); }
// round-to-nearest-even f32 -> bf16 bits
__device__ __forceinline__ unsigned short f2bu(float f) {
    unsigned u = __float_as_uint(f);
    return (unsigned short)((u + 0x7FFFu + ((u >> 16) & 1u)) >> 16);
}

// ---------------- CSR build ----------------
__global__ void k_hist(const int* __restrict__ recv, int* __restrict__ cnt) {
    int e = blockIdx.x * blockDim.x + threadIdx.x;
    if (e < EE) {
        int r = recv[e];
        r = ((unsigned)r < NN) ? r : 0;
        atomicAdd(&cnt[r], 1);
    }
}

__global__ void k_scan(const int* __restrict__ cnt, int* __restrict__ offs,
                       int* __restrict__ cur) {
    __shared__ int sums[1024];
    const int t = threadIdx.x;
    const int chunk = (NN + 1023) / 1024;  // 10
    const int start = t * chunk;
    int local = 0;
    for (int i = 0; i < chunk; i++) {
        int idx = start + i;
        if (idx < NN) local += cnt[idx];
    }
    sums[t] = local;
    __syncthreads();
    for (int ofs = 1; ofs < 1024; ofs <<= 1) {
        int u = (t >= ofs) ? sums[t - ofs] : 0;
        __syncthreads();
        sums[t] += u;
        __syncthreads();
    }
    int base = (t == 0) ? 0 : sums[t - 1];
    for (int i = 0; i < chunk; i++) {
        int idx = start + i;
        if (idx < NN) {
            offs[idx] = base;
            cur[idx] = base;
            base += cnt[idx];
        }
    }
    if (t == 0) offs[NN] = sums[1023];
}

__global__ void k_fill(const int* __restrict__ recv, int* __restrict__ cur,
                       int* __restrict__ csr) {
    int e = blockIdx.x * blockDim.x + threadIdx.x;
    if (e < EE) {
        int r = recv[e];
        r = ((unsigned)r < NN) ? r : 0;
        int slot = atomicAdd(&cur[r], 1);
        if ((unsigned)slot < EE) csr[slot] = e;
    }
}

// ---------------- transpose W_rad2 [64][640] f32 -> w2t [640][64] bf16 -----
__global__ void k_w2t(const float* __restrict__ W_rad2,
                      unsigned short* __restrict__ w2t) {
    int i = blockIdx.x * 256 + threadIdx.x;
    if (i < 640 * 64) {
        int n = i >> 6, k = i & 63;
        w2t[i] = f2bu(W_rad2[k * 640 + n]);
    }
}

// ---------------- node pre: h_s = s@W_up_s, h_v = v@W_up_v (bf16 out) ------
__global__ __launch_bounds__(512) void k_pre(
    const float* __restrict__ node_feats,
    const float* __restrict__ W_up_s,
    const float* __restrict__ W_up_v,
    __hip_bfloat16* __restrict__ h) {
    const int sub = threadIdx.x >> 7, d = threadIdx.x & 127;
    const int n = blockIdx.x * 4 + sub;
    __shared__ float sv[4][512];
    const float* nf = node_feats + (size_t)n * 512;
    ((float4*)sv[sub])[d] = ((const float4*)nf)[d];
    __syncthreads();
    float as = 0.f, a0 = 0.f, a1 = 0.f, a2 = 0.f;
    for (int c = 0; c < 128; c++) {
        const float wus = W_up_s[c * 128 + d];
        const float wuv = W_up_v[c * 128 + d];
        as += sv[sub][c] * wus;
        a0 += sv[sub][128 + c * 3 + 0] * wuv;
        a1 += sv[sub][128 + c * 3 + 1] * wuv;
        a2 += sv[sub][128 + c * 3 + 2] * wuv;
    }
    unsigned short* hn = (unsigned short*)(h + (size_t)n * 512);
    hn[d] = f2bu(as);
    hn[128 + d * 3 + 0] = f2bu(a0);
    hn[128 + d * 3 + 1] = f2bu(a1);
    hn[128 + d * 3 + 2] = f2bu(a2);
}

// ---------------- MFMA edge kernel: 1 wave per receiver --------------------
__global__ __launch_bounds__(256) void k_edge_mfma(
    const float* __restrict__ vectors,
    const float* __restrict__ radial,
    const int* __restrict__ senders,
    const float* __restrict__ W_rad1,
    const unsigned short* __restrict__ w2t,   // [640][64] bf16
    const __hip_bfloat16* __restrict__ h,
    const int* __restrict__ offs, const int* __restrict__ csr,
    __hip_bfloat16* __restrict__ agg_g) {
    __shared__ unsigned short w1s[8 * 64];  // W_rad1 bf16, 1 KB
    const int tid = threadIdx.x;
    const int lane = tid & 63, wv = tid >> 6;
    for (int i = tid; i < 512; i += 256) w1s[i] = f2bu(W_rad1[i]);
    __syncthreads();
    const int n = blockIdx.x * 4 + wv;
    const int start = offs[n];
    const int deg = offs[n + 1] - start;
    const int row = lane & 15, quad = lane >> 4;

    float acc_s[8], av0[8], av1[8], av2[8];
#pragma unroll
    for (int t = 0; t < 8; t++) { acc_s[t] = 0.f; av0[t] = 0.f; av1[t] = 0.f; av2[t] = 0.f; }

    for (int g0 = 0; g0 < deg; g0 += 16) {
        // --- per-lane edge meta (edge index = row; quads duplicate) ---
        int idx = start + g0 + row;
        int lim = start + deg - 1;
        int e = csr[idx < lim ? idx : lim];
        e = ((unsigned)e < EE) ? e : 0;
        int j = senders[e];
        j = ((unsigned)j < NN) ? j : 0;
        const float vx = vectors[e * 3 + 0];
        const float vy = vectors[e * 3 + 1];
        const float vz = vectors[e * 3 + 2];
        const float inr = 1.7320508075688772f /
                          (sqrtf(vx * vx + vy * vy + vz * vz) + 1e-9f);
        const float y0 = vx * inr, y1 = vy * inr, y2 = vz * inr;
        // --- radial embedding (8 f32) ---
        const float4 r0 = *(const float4*)(radial + (size_t)e * 8);
        const float4 r1 = *(const float4*)(radial + (size_t)e * 8 + 4);
        const float radv[8] = {r0.x, r0.y, r0.z, r0.w, r1.x, r1.y, r1.z, r1.w};
        // --- hid units quad*8..+7 and 32+quad*8..+7 for edge `row` ---
        float h0[8], h1[8];
#pragma unroll
        for (int u = 0; u < 8; u++) { h0[u] = 0.f; h1[u] = 0.f; }
#pragma unroll
        for (int r = 0; r < 8; r++) {
            const uint4 a = *(const uint4*)&w1s[r * 64 + quad * 8];
            const uint4 b = *(const uint4*)&w1s[r * 64 + 32 + quad * 8];
            const float rr = radv[r];
            h0[0] += rr * bflo(a.x); h0[1] += rr * bfhi(a.x);
            h0[2] += rr * bflo(a.y); h0[3] += rr * bfhi(a.y);
            h0[4] += rr * bflo(a.z); h0[5] += rr * bfhi(a.z);
            h0[6] += rr * bflo(a.w); h0[7] += rr * bfhi(a.w);
            h1[0] += rr * bflo(b.x); h1[1] += rr * bfhi(b.x);
            h1[2] += rr * bflo(b.y); h1[3] += rr * bfhi(b.y);
            h1[4] += rr * bflo(b.z); h1[5] += rr * bfhi(b.z);
            h1[6] += rr * bflo(b.w); h1[7] += rr * bfhi(b.w);
        }
        union { s16x8 v; unsigned short u[8]; } A0, A1;
#pragma unroll
        for (int u = 0; u < 8; u++) {
            const float s0 = h0[u] / (1.f + __expf(-h0[u]));
            const float s1 = h1[u] / (1.f + __expf(-h1[u]));
            A0.u[u] = f2bu(s0);
            A1.u[u] = f2bu(s1);
        }
        // --- broadcast meta for this quad's 4 C-rows ---
        int jr[4]; float yr0[4], yr1[4], yr2[4]; bool vr[4];
#pragma unroll
        for (int rg = 0; rg < 4; rg++) {
            const int src = quad * 4 + rg;
            jr[rg] = __shfl(j, src);
            yr0[rg] = __shfl(y0, src);
            yr1[rg] = __shfl(y1, src);
            yr2[rg] = __shfl(y2, src);
            vr[rg] = (g0 + src) < deg;
        }
        // --- 8 tile-groups: each lane gets channel c = 16t+row ---
#pragma unroll
        for (int t = 0; t < 8; t++) {
            f32x4 C[5];
#pragma unroll
            for (int p = 0; p < 5; p++) {
                const unsigned short* bp =
                    w2t + (size_t)(128 * p + 16 * t + row) * 64 + quad * 8;
                const s16x8 B0 = *(const s16x8*)(bp);
                const s16x8 B1 = *(const s16x8*)(bp + 32);
                f32x4 z = {0.f, 0.f, 0.f, 0.f};
                z = __builtin_amdgcn_mfma_f32_16x16x32_bf16(A0.v, B0, z, 0, 0, 0);
                z = __builtin_amdgcn_mfma_f32_16x16x32_bf16(A1.v, B1, z, 0, 0, 0);
                C[p] = z;
            }
            const int c = 16 * t + row;
#pragma unroll
            for (int rg = 0; rg < 4; rg++) {
                if (vr[rg]) {
                    const unsigned short* hj =
                        (const unsigned short*)h + (size_t)jr[rg] * 512;
                    const float sj = bfu(hj[c]);
                    const float a0 = bfu(hj[128 + 3 * c + 0]);
                    const float a1 = bfu(hj[128 + 3 * c + 1]);
                    const float a2 = bfu(hj[128 + 3 * c + 2]);
                    const float w0 = C[0][rg], w1p = C[1][rg], w2p = C[2][rg];
                    const float w3 = C[3][rg], w4 = C[4][rg];
                    const float d = a0 * yr0[rg] + a1 * yr1[rg] + a2 * yr2[rg];
                    const float cr0 = a1 * yr2[rg] - a2 * yr1[rg];
                    const float cr1 = a2 * yr0[rg] - a0 * yr2[rg];
                    const float cr2 = a0 * yr1[rg] - a1 * yr0[rg];
                    acc_s[t] += w0 * sj + w3 * d;
                    av0[t] += w1p * sj * yr0[rg] + w2p * a0 + w4 * cr0;
                    av1[t] += w1p * sj * yr1[rg] + w2p * a1 + w4 * cr1;
                    av2[t] += w1p * sj * yr2[rg] + w2p * a2 + w4 * cr2;
                }
            }
        }
    }
    // --- cross-quad reduction (rows live in different quads) ---
#pragma unroll
    for (int t = 0; t < 8; t++) {
        acc_s[t] += __shfl_xor(acc_s[t], 16); acc_s[t] += __shfl_xor(acc_s[t], 32);
        av0[t] += __shfl_xor(av0[t], 16);     av0[t] += __shfl_xor(av0[t], 32);
        av1[t] += __shfl_xor(av1[t], 16);     av1[t] += __shfl_xor(av1[t], 32);
        av2[t] += __shfl_xor(av2[t], 16);     av2[t] += __shfl_xor(av2[t], 32);
    }
    if (lane < 16) {
        unsigned short* og = (unsigned short*)agg_g + (size_t)n * 512;
#pragma unroll
        for (int t = 0; t < 8; t++) {
            const int c = 16 * t + lane;
            og[c] = f2bu(acc_s[t]);
            og[128 + 3 * c + 0] = f2bu(av0[t]);
            og[128 + 3 * c + 1] = f2bu(av1[t]);
            og[128 + 3 * c + 2] = f2bu(av2[t]);
        }
    }
}

// ---------------- node post: down/prod/lin/skip/readout ----------------
__global__ __launch_bounds__(512) void k_post(
    const float* __restrict__ node_feats,
    const int* __restrict__ specie,
    const __hip_bfloat16* __restrict__ agg_g,
    const float* __restrict__ W_down_s,
    const float* __restrict__ W_down_v,
    const float* __restrict__ W_skip_s,
    const float* __restrict__ W_skip_v,
    const float* __restrict__ W_prod_s,
    const float* __restrict__ W_prod_v,
    const float* __restrict__ W_lin_s,
    const float* __restrict__ W_lin_v,
    const float* __restrict__ W_ro,
    float* __restrict__ d_out) {
    const int sub = threadIdx.x >> 7, d = threadIdx.x & 127;
    const int n = blockIdx.x * 4 + sub;
    __shared__ float sv[4][512];
    __shared__ float ag[4][512];
    __shared__ float pl[4][512];
    __shared__ float red[4][2];
    const float* nf = node_feats + (size_t)n * 512;
    const __hip_bfloat16* agp = agg_g + (size_t)n * 512;
    ((float4*)sv[sub])[d] = ((const float4*)nf)[d];
    for (int i = d; i < 512; i += 128) ag[sub][i] = b2f(agp[i]);
    __syncthreads();
    int spec = specie[n];
    spec = ((unsigned)spec < 10) ? spec : 0;
    const float* Wss = W_skip_s + (size_t)spec * 16384;
    const float* Wsv = W_skip_v + (size_t)spec * 16384;
    float scs = 0, scv0 = 0, scv1 = 0, scv2 = 0, fs = 0, fv0 = 0, fv1 = 0, fv2 = 0;
    for (int c = 0; c < 128; c++) {
        const float s_c = sv[sub][c];
        const float v0 = sv[sub][128 + c * 3 + 0];
        const float v1 = sv[sub][128 + c * 3 + 1];
        const float v2 = sv[sub][128 + c * 3 + 2];
        const float a_c = ag[sub][c];
        const float a0 = ag[sub][128 + c * 3 + 0];
        const float a1 = ag[sub][128 + c * 3 + 1];
        const float a2 = ag[sub][128 + c * 3 + 2];
        const float wss = Wss[c * 128 + d];
        const float wsv = Wsv[c * 128 + d];
        const float wds = W_down_s[c * 128 + d];
        const float wdv = W_down_v[c * 128 + d];
        scs += s_c * wss;
        scv0 += v0 * wsv; scv1 += v1 * wsv; scv2 += v2 * wsv;
        fs += a_c * wds;
        fv0 += a0 * wdv; fv1 += a1 * wdv; fv2 += a2 * wdv;
    }
    fs *= FEPS; fv0 *= FEPS; fv1 *= FEPS; fv2 *= FEPS;
    const float ps = fs * W_prod_s[spec * 384 + d]
                   + fs * fs * W_prod_s[spec * 384 + 128 + d]
                   + (fv0 * fv0 + fv1 * fv1 + fv2 * fv2) * W_prod_s[spec * 384 + 256 + d];
    const float pw0 = W_prod_v[spec * 256 + d];
    const float pw1 = W_prod_v[spec * 256 + 128 + d];
    const float pv0 = fv0 * pw0 + fs * fv0 * pw1;
    const float pv1 = fv1 * pw0 + fs * fv1 * pw1;
    const float pv2 = fv2 * pw0 + fs * fv2 * pw1;
    pl[sub][d] = ps;
    pl[sub][128 + d * 3 + 0] = pv0;
    pl[sub][128 + d * 3 + 1] = pv1;
    pl[sub][128 + d * 3 + 2] = pv2;
    __syncthreads();
    float outs = scs, ov0 = scv0, ov1 = scv1, ov2 = scv2;
    for (int c = 0; c < 128; c++) {
        const float wls = W_lin_s[c * 128 + d];
        const float wlv = W_lin_v[c * 128 + d];
        outs += pl[sub][c] * wls;
        ov0 += pl[sub][128 + c * 3 + 0] * wlv;
        ov1 += pl[sub][128 + c * 3 + 1] * wlv;
        ov2 += pl[sub][128 + c * 3 + 2] * wlv;
    }
    float* o1 = d_out + NN + (size_t)n * 512;
    o1[d] = outs;
    o1[128 + d * 3 + 0] = ov0;
    o1[128 + d * 3 + 1] = ov1;
    o1[128 + d * 3 + 2] = ov2;
    float r = outs * W_ro[d];
#pragma unroll
    for (int o = 32; o > 0; o >>= 1) r += __shfl_down(r, o);
    const int lane = threadIdx.x & 63;
    const int wv_in_sub = (threadIdx.x >> 6) & 1;
    if (lane == 0) red[sub][wv_in_sub] = r;
    __syncthreads();
    if (d == 0) d_out[n] = red[sub][0] + red[sub][1];
}

extern "C" void kernel_launch(void* const* d_in, const int* in_sizes, int n_in,
                              void* d_out, int out_size, void* d_ws, size_t ws_size,
                              hipStream_t stream) {
    const float* vectors    = (const float*)d_in[0];
    const float* node_feats = (const float*)d_in[1];
    const int*   specie     = (const int*)d_in[2];
    const float* radial     = (const float*)d_in[3];
    const int*   senders    = (const int*)d_in[4];
    const int*   receivers  = (const int*)d_in[5];
    const float* W_up_s     = (const float*)d_in[6];
    const float* W_up_v     = (const float*)d_in[7];
    const float* W_rad1     = (const float*)d_in[8];
    const float* W_rad2     = (const float*)d_in[9];
    const float* W_down_s   = (const float*)d_in[10];
    const float* W_down_v   = (const float*)d_in[11];
    const float* W_skip_s   = (const float*)d_in[12];
    const float* W_skip_v   = (const float*)d_in[13];
    const float* W_prod_s   = (const float*)d_in[14];
    const float* W_prod_v   = (const float*)d_in[15];
    const float* W_lin_s    = (const float*)d_in[16];
    const float* W_lin_v    = (const float*)d_in[17];
    const float* W_ro       = (const float*)d_in[18];
    float* out = (float*)d_out;

    // workspace carve (~22.2 MB): CSR first, bf16 h/agg, w2t table
    char* w = (char*)d_ws;
    auto align256 = [](size_t x) { return (x + 255) & ~(size_t)255; };
    int* cnt  = (int*)w;              w += align256((size_t)NN * 4);
    int* offs = (int*)w;              w += align256((size_t)(NN + 1) * 4);
    int* cur  = (int*)w;              w += align256((size_t)NN * 4);
    int* csr  = (int*)w;              w += align256((size_t)EE * 4);
    __hip_bfloat16* h     = (__hip_bfloat16*)w;  w += align256((size_t)NN * 512 * 2);
    __hip_bfloat16* agg_g = (__hip_bfloat16*)w;  w += align256((size_t)NN * 512 * 2);
    unsigned short* w2t   = (unsigned short*)w;  // 640*64*2 = 80 KB

    hipMemsetAsync(cnt, 0, NN * sizeof(int), stream);
    k_hist<<<(EE + 255) / 256, 256, 0, stream>>>(receivers, cnt);
    k_scan<<<1, 1024, 0, stream>>>(cnt, offs, cur);
    k_fill<<<(EE + 255) / 256, 256, 0, stream>>>(receivers, cur, csr);
    k_w2t<<<160, 256, 0, stream>>>(W_rad2, w2t);
    k_pre<<<NN / 4, 512, 0, stream>>>(node_feats, W_up_s, W_up_v, h);
    k_edge_mfma<<<NN / 4, 256, 0, stream>>>(vectors, radial, senders, W_rad1,
                                            w2t, h, offs, csr, agg_g);
    k_post<<<NN / 4, 512, 0, stream>>>(node_feats, specie, agg_g,
                                       W_down_s, W_down_v, W_skip_s, W_skip_v,
                                       W_prod_s, W_prod_v, W_lin_s, W_lin_v,
                                       W_ro, out);
}